// Round 1
// baseline (17905.830 us; speedup 1.0000x reference)
//
#include <hip/hip_runtime.h>
#include <hip/hip_bf16.h>
#include <math.h>

#define NGRAPHS 256

// ---------------- degree ----------------
__global__ __launch_bounds__(256) void k_degree(const int* __restrict__ dst, int* __restrict__ cnt, int E) {
    int e = blockIdx.x * 256 + threadIdx.x;
    if (e < E) atomicAdd(&cnt[dst[e]], 1);
}

// ---------------- layer-1 pre-matmul: y = x @ w_rel1  (N x 64 @ 64 x 16) ----------------
__global__ __launch_bounds__(256) void k_mm_rel1(const float* __restrict__ x, const float* __restrict__ w,
                                                 float* __restrict__ y, int N) {
    __shared__ float ws[64 * 16];
    for (int i = threadIdx.x; i < 64 * 16; i += 256) ws[i] = w[i];
    __syncthreads();
    int n = blockIdx.x * 256 + threadIdx.x;
    if (n >= N) return;
    float xr[64];
    const float4* xp = (const float4*)(x + (size_t)n * 64);
#pragma unroll
    for (int i = 0; i < 16; i++) {
        float4 v = xp[i];
        xr[4 * i + 0] = v.x; xr[4 * i + 1] = v.y; xr[4 * i + 2] = v.z; xr[4 * i + 3] = v.w;
    }
    float acc[16];
#pragma unroll
    for (int j = 0; j < 16; j++) acc[j] = 0.f;
#pragma unroll
    for (int ci = 0; ci < 64; ci++) {
        float xv = xr[ci];
#pragma unroll
        for (int j = 0; j < 16; j++) acc[j] += xv * ws[ci * 16 + j];
    }
    float4* yp = (float4*)(y + (size_t)n * 16);
#pragma unroll
    for (int j = 0; j < 4; j++) {
        float4 v; v.x = acc[4 * j]; v.y = acc[4 * j + 1]; v.z = acc[4 * j + 2]; v.w = acc[4 * j + 3];
        yp[j] = v;
    }
}

// ---------------- scatter-add of C channels per edge ----------------
template <int C>
__global__ __launch_bounds__(256) void k_scatter(const int* __restrict__ src, const int* __restrict__ dst,
                                                 const float* __restrict__ h, float* __restrict__ msg, int E) {
    int e = blockIdx.x * 256 + threadIdx.x;
    if (e >= E) return;
    int s = src[e], d = dst[e];
    const float4* hp = (const float4*)(h + (size_t)s * C);
    float* mp = msg + (size_t)d * C;
#pragma unroll
    for (int i = 0; i < C / 4; i++) {
        float4 v = hp[i];
        atomicAdd(mp + 4 * i + 0, v.x);
        atomicAdd(mp + 4 * i + 1, v.y);
        atomicAdd(mp + 4 * i + 2, v.z);
        atomicAdd(mp + 4 * i + 3, v.w);
    }
}

// ---------------- node update: out = agg@w_rel + h@w_root + b, + BN partial stats ----------------
// PRE=true: msg already holds CO channels (pre-multiplied by w_rel), so out = msg/cnt + h@w_root + b
template <int CI, int CO, bool PRE>
__global__ __launch_bounds__(256) void k_node(const float* __restrict__ h, const float* __restrict__ msg,
                                              const int* __restrict__ cnt, const float* __restrict__ w_rel,
                                              const float* __restrict__ w_root, const float* __restrict__ bias,
                                              float* __restrict__ out, float* __restrict__ stats, int N) {
    __shared__ float s_rel[CI * CO];
    __shared__ float s_root[CI * CO];
    __shared__ float s_b[CO];
    if (!PRE)
        for (int i = threadIdx.x; i < CI * CO; i += 256) s_rel[i] = w_rel[i];
    for (int i = threadIdx.x; i < CI * CO; i += 256) s_root[i] = w_root[i];
    if (threadIdx.x < CO) s_b[threadIdx.x] = bias[threadIdx.x];
    __syncthreads();

    int n = blockIdx.x * 256 + threadIdx.x;
    bool valid = n < N;
    int nn = valid ? n : 0;

    float rec;
    { int c = cnt[nn]; rec = 1.0f / (float)(c > 1 ? c : 1); }

    float hr[CI];
    {
        const float4* hp = (const float4*)(h + (size_t)nn * CI);
#pragma unroll
        for (int i = 0; i < CI / 4; i++) {
            float4 v = hp[i];
            hr[4 * i + 0] = v.x; hr[4 * i + 1] = v.y; hr[4 * i + 2] = v.z; hr[4 * i + 3] = v.w;
        }
    }

    float acc[CO];
    if (PRE) {
        const float4* mp = (const float4*)(msg + (size_t)nn * CO);
#pragma unroll
        for (int i = 0; i < CO / 4; i++) {
            float4 v = mp[i];
            acc[4 * i + 0] = v.x * rec + s_b[4 * i + 0];
            acc[4 * i + 1] = v.y * rec + s_b[4 * i + 1];
            acc[4 * i + 2] = v.z * rec + s_b[4 * i + 2];
            acc[4 * i + 3] = v.w * rec + s_b[4 * i + 3];
        }
    } else {
        float ar[CI];
        const float4* mp = (const float4*)(msg + (size_t)nn * CI);
#pragma unroll
        for (int i = 0; i < CI / 4; i++) {
            float4 v = mp[i];
            ar[4 * i + 0] = v.x * rec; ar[4 * i + 1] = v.y * rec;
            ar[4 * i + 2] = v.z * rec; ar[4 * i + 3] = v.w * rec;
        }
#pragma unroll
        for (int co = 0; co < CO; co++) acc[co] = s_b[co];
#pragma unroll
        for (int ci = 0; ci < CI; ci++) {
            float a = ar[ci];
#pragma unroll
            for (int co = 0; co < CO; co++) acc[co] += a * s_rel[ci * CO + co];
        }
    }
#pragma unroll
    for (int ci = 0; ci < CI; ci++) {
        float hv = hr[ci];
#pragma unroll
        for (int co = 0; co < CO; co++) acc[co] += hv * s_root[ci * CO + co];
    }

    if (!valid) {
#pragma unroll
        for (int co = 0; co < CO; co++) acc[co] = 0.f;
    }

    if (valid) {
        float4* op = (float4*)(out + (size_t)n * CO);
#pragma unroll
        for (int i = 0; i < CO / 4; i++) {
            float4 v;
            v.x = acc[4 * i + 0]; v.y = acc[4 * i + 1]; v.z = acc[4 * i + 2]; v.w = acc[4 * i + 3];
            op[i] = v;
        }
    }

    // BN partial stats: per-wave butterfly reduce sum & sumsq, one atomic per wave per channel
#pragma unroll
    for (int co = 0; co < CO; co++) {
        float s = acc[co];
        float q = s * s;
#pragma unroll
        for (int off = 1; off < 64; off <<= 1) {
            s += __shfl_xor(s, off, 64);
            q += __shfl_xor(q, off, 64);
        }
        if ((threadIdx.x & 63) == 0) {
            atomicAdd(&stats[co], s);
            atomicAdd(&stats[64 + co], q);
        }
    }
}

// ---------------- BN finalize: scale/shift per channel ----------------
__global__ void k_bn_final(float* __restrict__ stats, const float* __restrict__ g, const float* __restrict__ be,
                           int CO, float invN) {
    int c = threadIdx.x;
    if (c < CO) {
        float mean = stats[c] * invN;
        float var = stats[64 + c] * invN - mean * mean;
        float sc = g[c] * rsqrtf(var + 1e-5f);
        stats[128 + c] = sc;
        stats[192 + c] = be[c] - mean * sc;
    }
}

// ---------------- BN apply + ELU, in place ----------------
template <int CO>
__global__ __launch_bounds__(256) void k_bn_elu(float* __restrict__ h, const float* __restrict__ stats, int N) {
    __shared__ float sc[CO], sh[CO];
    if (threadIdx.x < CO) {
        sc[threadIdx.x] = stats[128 + threadIdx.x];
        sh[threadIdx.x] = stats[192 + threadIdx.x];
    }
    __syncthreads();
    int total = N * (CO / 4);
    int i = blockIdx.x * 256 + threadIdx.x;
    if (i >= total) return;
    float4 v = ((float4*)h)[i];
    int cq = (i % (CO / 4)) * 4;
    v.x = v.x * sc[cq + 0] + sh[cq + 0];
    v.y = v.y * sc[cq + 1] + sh[cq + 1];
    v.z = v.z * sc[cq + 2] + sh[cq + 2];
    v.w = v.w * sc[cq + 3] + sh[cq + 3];
    v.x = v.x > 0.f ? v.x : expm1f(v.x);
    v.y = v.y > 0.f ? v.y : expm1f(v.y);
    v.z = v.z > 0.f ? v.z : expm1f(v.z);
    v.w = v.w > 0.f ? v.w : expm1f(v.w);
    ((float4*)h)[i] = v;
}

// ---------------- global mean pool (batch is sorted): run-length segmented reduce ----------------
__global__ __launch_bounds__(256) void k_pool(const float* __restrict__ h, const int* __restrict__ batch,
                                              float* __restrict__ pooled, float* __restrict__ cntg, int N) {
    int lane = threadIdx.x & 63;
    int wid = blockIdx.x * 4 + (threadIdx.x >> 6);
    int n0 = wid * 64;
    if (n0 >= N) return;
    int nmax = N - n0; if (nmax > 64) nmax = 64;
    int cur = batch[n0];
    float acc = 0.f;
    int run = 0;
    for (int k = 0; k < nmax; k++) {
        int g = batch[n0 + k];
        if (g != cur) {
            atomicAdd(&pooled[(size_t)cur * 64 + lane], acc);
            if (lane == 0) atomicAdd(&cntg[cur], (float)run);
            cur = g; acc = 0.f; run = 0;
        }
        acc += h[(size_t)(n0 + k) * 64 + lane];
        run++;
    }
    atomicAdd(&pooled[(size_t)cur * 64 + lane], acc);
    if (lane == 0) atomicAdd(&cntg[cur], (float)run);
}

// ---------------- head: mean-div, lin1+relu, lin2, log_softmax ----------------
__global__ __launch_bounds__(256) void k_head(const float* __restrict__ pooled, const float* __restrict__ cntg,
                                              const float* __restrict__ w1, const float* __restrict__ b1,
                                              const float* __restrict__ w2, const float* __restrict__ b2,
                                              float* __restrict__ out) {
    __shared__ float sw1[64 * 64];
    __shared__ float sw2[64 * 10];
    __shared__ float sb1[64];
    __shared__ float sb2[10];
    for (int i = threadIdx.x; i < 64 * 64; i += 256) sw1[i] = w1[i];
    for (int i = threadIdx.x; i < 64 * 10; i += 256) sw2[i] = w2[i];
    if (threadIdx.x < 64) sb1[threadIdx.x] = b1[threadIdx.x];
    if (threadIdx.x < 10) sb2[threadIdx.x] = b2[threadIdx.x];
    __syncthreads();
    int g = threadIdx.x;  // 256 threads == 256 graphs
    float rec = 1.0f / fmaxf(cntg[g], 1.0f);
    float p[64];
#pragma unroll
    for (int k = 0; k < 64; k++) p[k] = pooled[(size_t)g * 64 + k] * rec;
    float z[64];
#pragma unroll
    for (int j = 0; j < 64; j++) {
        float a = sb1[j];
#pragma unroll
        for (int k = 0; k < 64; k++) a += p[k] * sw1[k * 64 + j];
        z[j] = fmaxf(a, 0.f);
    }
    float lg[10];
#pragma unroll
    for (int j = 0; j < 10; j++) {
        float a = sb2[j];
#pragma unroll
        for (int k = 0; k < 64; k++) a += z[k] * sw2[k * 10 + j];
        lg[j] = a;
    }
    float m = -1e30f;
#pragma unroll
    for (int j = 0; j < 10; j++) m = fmaxf(m, lg[j]);
    float s = 0.f;
#pragma unroll
    for (int j = 0; j < 10; j++) s += expf(lg[j] - m);
    float lse = m + logf(s);
#pragma unroll
    for (int j = 0; j < 10; j++) out[(size_t)g * 10 + j] = lg[j] - lse;
}

extern "C" void kernel_launch(void* const* d_in, const int* in_sizes, int n_in,
                              void* d_out, int out_size, void* d_ws, size_t ws_size,
                              hipStream_t stream) {
    const float* x = (const float*)d_in[0];
    const int* ei = (const int*)d_in[1];
    const int* batch = (const int*)d_in[2];
    const int N = in_sizes[0] / 64;
    const int E = in_sizes[1] / 2;
    const int* src = ei;
    const int* dst = ei + E;

    const float* w_rel1 = (const float*)d_in[3];
    const float* w_root1 = (const float*)d_in[4];
    const float* b1 = (const float*)d_in[5];
    const float* g1 = (const float*)d_in[6];
    const float* be1 = (const float*)d_in[7];
    const float* w_rel2 = (const float*)d_in[8];
    const float* w_root2 = (const float*)d_in[9];
    const float* b2 = (const float*)d_in[10];
    const float* g2 = (const float*)d_in[11];
    const float* be2 = (const float*)d_in[12];
    const float* w_rel3 = (const float*)d_in[13];
    const float* w_root3 = (const float*)d_in[14];
    const float* b3 = (const float*)d_in[15];
    const float* g3 = (const float*)d_in[16];
    const float* be3 = (const float*)d_in[17];
    const float* w_rel4 = (const float*)d_in[18];
    const float* w_root4 = (const float*)d_in[19];
    const float* b4 = (const float*)d_in[20];
    const float* g4 = (const float*)d_in[21];
    const float* be4 = (const float*)d_in[22];
    const float* w_lin1 = (const float*)d_in[23];
    const float* b_lin1 = (const float*)d_in[24];
    const float* w_lin2 = (const float*)d_in[25];
    const float* b_lin2 = (const float*)d_in[26];

    char* ws = (char*)d_ws;
    size_t off = 0;
    auto alloc = [&](size_t bytes) { size_t o = off; off += (bytes + 255) & ~(size_t)255; return o; };
    int* cnt = (int*)(ws + alloc((size_t)N * 4));
    float* msg = (float*)(ws + alloc((size_t)N * 32 * 4));
    float* y1 = (float*)(ws + alloc((size_t)N * 16 * 4));
    float* bufA = (float*)(ws + alloc((size_t)N * 64 * 4));
    float* bufB = (float*)(ws + alloc((size_t)N * 64 * 4));
    float* stats = (float*)(ws + alloc(4 * 256 * 4));
    float* pooled = (float*)(ws + alloc((size_t)(NGRAPHS * 64 + NGRAPHS) * 4));
    float* cntg = pooled + NGRAPHS * 64;

    hipMemsetAsync(cnt, 0, (size_t)N * 4, stream);
    hipMemsetAsync(stats, 0, 4 * 256 * 4, stream);
    hipMemsetAsync(pooled, 0, (size_t)(NGRAPHS * 64 + NGRAPHS) * 4, stream);

    const int ebl = (E + 255) / 256;
    const int nbl = (N + 255) / 256;
    const float invN = 1.0f / (float)N;

    k_degree<<<ebl, 256, 0, stream>>>(dst, cnt, E);

    // ---- Layer 1 (64 -> 16): matmul first, aggregate 16 channels ----
    k_mm_rel1<<<nbl, 256, 0, stream>>>(x, w_rel1, y1, N);
    hipMemsetAsync(msg, 0, (size_t)N * 16 * 4, stream);
    k_scatter<16><<<ebl, 256, 0, stream>>>(src, dst, y1, msg, E);
    k_node<64, 16, true><<<nbl, 256, 0, stream>>>(x, msg, cnt, nullptr, w_root1, b1, bufA, stats + 0, N);
    k_bn_final<<<1, 64, 0, stream>>>(stats + 0, g1, be1, 16, invN);
    k_bn_elu<16><<<(N * 4 + 255) / 256, 256, 0, stream>>>(bufA, stats + 0, N);

    // ---- Layer 2 (16 -> 32): aggregate input (16 ch) ----
    hipMemsetAsync(msg, 0, (size_t)N * 16 * 4, stream);
    k_scatter<16><<<ebl, 256, 0, stream>>>(src, dst, bufA, msg, E);
    k_node<16, 32, false><<<nbl, 256, 0, stream>>>(bufA, msg, cnt, w_rel2, w_root2, b2, bufB, stats + 256, N);
    k_bn_final<<<1, 64, 0, stream>>>(stats + 256, g2, be2, 32, invN);
    k_bn_elu<32><<<(N * 8 + 255) / 256, 256, 0, stream>>>(bufB, stats + 256, N);

    // ---- Layer 3 (32 -> 32) ----
    hipMemsetAsync(msg, 0, (size_t)N * 32 * 4, stream);
    k_scatter<32><<<ebl, 256, 0, stream>>>(src, dst, bufB, msg, E);
    k_node<32, 32, false><<<nbl, 256, 0, stream>>>(bufB, msg, cnt, w_rel3, w_root3, b3, bufA, stats + 512, N);
    k_bn_final<<<1, 64, 0, stream>>>(stats + 512, g3, be3, 32, invN);
    k_bn_elu<32><<<(N * 8 + 255) / 256, 256, 0, stream>>>(bufA, stats + 512, N);

    // ---- Layer 4 (32 -> 64) ----
    hipMemsetAsync(msg, 0, (size_t)N * 32 * 4, stream);
    k_scatter<32><<<ebl, 256, 0, stream>>>(src, dst, bufA, msg, E);
    k_node<32, 64, false><<<nbl, 256, 0, stream>>>(bufA, msg, cnt, w_rel4, w_root4, b4, bufB, stats + 768, N);
    k_bn_final<<<1, 64, 0, stream>>>(stats + 768, g4, be4, 64, invN);
    k_bn_elu<64><<<(N * 16 + 255) / 256, 256, 0, stream>>>(bufB, stats + 768, N);

    // ---- global mean pool + head ----
    int waves = (N + 63) / 64;
    k_pool<<<(waves + 3) / 4, 256, 0, stream>>>(bufB, batch, pooled, cntg, N);
    k_head<<<1, 256, 0, stream>>>(pooled, cntg, w_lin1, b_lin1, w_lin2, b_lin2, (float*)d_out);
}

// Round 2
// 3010.954 us; speedup vs baseline: 5.9469x; 5.9469x over previous
//
#include <hip/hip_runtime.h>
#include <hip/hip_bf16.h>
#include <math.h>

#define NGRAPHS 256

// ---------------- degree histogram ----------------
__global__ __launch_bounds__(256) void k_degree(const int* __restrict__ dst, int* __restrict__ cnt, int E) {
    int e = blockIdx.x * 256 + threadIdx.x;
    if (e < E) atomicAdd(&cnt[dst[e]], 1);
}

// ---------------- scan pass 1: per-block sums ----------------
__global__ __launch_bounds__(256) void k_scan1(const int* __restrict__ cnt, int* __restrict__ bsum, int N) {
    int i = blockIdx.x * 256 + threadIdx.x;
    int v = (i < N) ? cnt[i] : 0;
#pragma unroll
    for (int off = 1; off < 64; off <<= 1) v += __shfl_xor(v, off, 64);
    __shared__ int ws[4];
    if ((threadIdx.x & 63) == 0) ws[threadIdx.x >> 6] = v;
    __syncthreads();
    if (threadIdx.x == 0) bsum[blockIdx.x] = ws[0] + ws[1] + ws[2] + ws[3];
}

// ---------------- scan pass 2: exclusive scan of block sums (NB <= 512) ----------------
__global__ __launch_bounds__(512) void k_scan2(int* __restrict__ bsum, int NB) {
    __shared__ int s[512];
    int tid = threadIdx.x;
    int v = (tid < NB) ? bsum[tid] : 0;
    s[tid] = v;
    __syncthreads();
#pragma unroll
    for (int off = 1; off < 512; off <<= 1) {
        int t = (tid >= off) ? s[tid - off] : 0;
        __syncthreads();
        s[tid] += t;
        __syncthreads();
    }
    if (tid < NB) bsum[tid] = s[tid] - v;  // exclusive
}

// ---------------- scan pass 3: per-block exclusive scan + offset -> row_start ----------------
__global__ __launch_bounds__(256) void k_scan3(const int* __restrict__ cnt, const int* __restrict__ bsum,
                                               int* __restrict__ row_start, int N) {
    __shared__ int s[256];
    int tid = threadIdx.x;
    int i = blockIdx.x * 256 + tid;
    int v = (i < N) ? cnt[i] : 0;
    s[tid] = v;
    __syncthreads();
#pragma unroll
    for (int off = 1; off < 256; off <<= 1) {
        int t = (tid >= off) ? s[tid - off] : 0;
        __syncthreads();
        s[tid] += t;
        __syncthreads();
    }
    if (i < N) row_start[i] = bsum[blockIdx.x] + s[tid] - v;
    if (i == N - 1) row_start[N] = bsum[blockIdx.x] + s[tid];
}

// ---------------- CSR fill ----------------
__global__ __launch_bounds__(256) void k_fill(const int* __restrict__ src, const int* __restrict__ dst,
                                              int* __restrict__ cursor, int* __restrict__ csr, int E) {
    int e = blockIdx.x * 256 + threadIdx.x;
    if (e >= E) return;
    int d = dst[e];
    int p = atomicAdd(&cursor[d], 1);
    csr[p] = src[e];
}

// ---------------- layer-1 pre-matmul: y = x @ w_rel1  (N x 64 @ 64 x 16) ----------------
__global__ __launch_bounds__(256) void k_mm_rel1(const float* __restrict__ x, const float* __restrict__ w,
                                                 float* __restrict__ y, int N) {
    __shared__ float ws[64 * 16];
    for (int i = threadIdx.x; i < 64 * 16; i += 256) ws[i] = w[i];
    __syncthreads();
    int n = blockIdx.x * 256 + threadIdx.x;
    if (n >= N) return;
    float xr[64];
    const float4* xp = (const float4*)(x + (size_t)n * 64);
#pragma unroll
    for (int i = 0; i < 16; i++) {
        float4 v = xp[i];
        xr[4 * i + 0] = v.x; xr[4 * i + 1] = v.y; xr[4 * i + 2] = v.z; xr[4 * i + 3] = v.w;
    }
    float acc[16];
#pragma unroll
    for (int j = 0; j < 16; j++) acc[j] = 0.f;
#pragma unroll
    for (int ci = 0; ci < 64; ci++) {
        float xv = xr[ci];
#pragma unroll
        for (int j = 0; j < 16; j++) acc[j] += xv * ws[ci * 16 + j];
    }
    float4* yp = (float4*)(y + (size_t)n * 16);
#pragma unroll
    for (int j = 0; j < 4; j++) {
        float4 v; v.x = acc[4 * j]; v.y = acc[4 * j + 1]; v.z = acc[4 * j + 2]; v.w = acc[4 * j + 3];
        yp[j] = v;
    }
}

// ---------------- gather-based mean aggregation: one wave per node ----------------
// lanes: [edge_subgroup][channel]; coalesced row-segment reads; shuffle cross-reduce
template <int C>
__global__ __launch_bounds__(256) void k_gather(const float* __restrict__ h, const int* __restrict__ row_start,
                                                const int* __restrict__ csr, float* __restrict__ agg, int N) {
    constexpr int EPP = 64 / C;  // edges per pass
    int lane = threadIdx.x & 63;
    int wid = blockIdx.x * 4 + (threadIdx.x >> 6);
    if (wid >= N) return;
    int r0 = row_start[wid];
    int deg = row_start[wid + 1] - r0;
    int c = lane & (C - 1);
    int es = lane / C;
    float acc = 0.f;
    for (int j = es; j < deg; j += EPP) {
        int s = csr[r0 + j];
        acc += h[(size_t)s * C + c];
    }
#pragma unroll
    for (int off = C; off < 64; off <<= 1) acc += __shfl_xor(acc, off, 64);
    if (lane < C) {
        float rec = 1.0f / (float)(deg > 0 ? deg : 1);
        agg[(size_t)wid * C + c] = acc * rec;
    }
}

// ---------------- node update: out = agg@w_rel + h@w_root + b, + BN partial stats ----------------
// PRE=true: agg already holds CO channels (pre-multiplied by w_rel): out = agg + h@w_root + b
template <int CI, int CO, bool PRE>
__global__ __launch_bounds__(256) void k_node(const float* __restrict__ h, const float* __restrict__ agg,
                                              const float* __restrict__ w_rel,
                                              const float* __restrict__ w_root, const float* __restrict__ bias,
                                              float* __restrict__ out, float* __restrict__ stats, int N) {
    __shared__ float s_rel[CI * CO];
    __shared__ float s_root[CI * CO];
    __shared__ float s_b[CO];
    if (!PRE)
        for (int i = threadIdx.x; i < CI * CO; i += 256) s_rel[i] = w_rel[i];
    for (int i = threadIdx.x; i < CI * CO; i += 256) s_root[i] = w_root[i];
    if (threadIdx.x < CO) s_b[threadIdx.x] = bias[threadIdx.x];
    __syncthreads();

    int n = blockIdx.x * 256 + threadIdx.x;
    bool valid = n < N;
    int nn = valid ? n : 0;

    float hr[CI];
    {
        const float4* hp = (const float4*)(h + (size_t)nn * CI);
#pragma unroll
        for (int i = 0; i < CI / 4; i++) {
            float4 v = hp[i];
            hr[4 * i + 0] = v.x; hr[4 * i + 1] = v.y; hr[4 * i + 2] = v.z; hr[4 * i + 3] = v.w;
        }
    }

    float acc[CO];
    if (PRE) {
        const float4* mp = (const float4*)(agg + (size_t)nn * CO);
#pragma unroll
        for (int i = 0; i < CO / 4; i++) {
            float4 v = mp[i];
            acc[4 * i + 0] = v.x + s_b[4 * i + 0];
            acc[4 * i + 1] = v.y + s_b[4 * i + 1];
            acc[4 * i + 2] = v.z + s_b[4 * i + 2];
            acc[4 * i + 3] = v.w + s_b[4 * i + 3];
        }
    } else {
        float ar[CI];
        const float4* mp = (const float4*)(agg + (size_t)nn * CI);
#pragma unroll
        for (int i = 0; i < CI / 4; i++) {
            float4 v = mp[i];
            ar[4 * i + 0] = v.x; ar[4 * i + 1] = v.y;
            ar[4 * i + 2] = v.z; ar[4 * i + 3] = v.w;
        }
#pragma unroll
        for (int co = 0; co < CO; co++) acc[co] = s_b[co];
#pragma unroll
        for (int ci = 0; ci < CI; ci++) {
            float a = ar[ci];
#pragma unroll
            for (int co = 0; co < CO; co++) acc[co] += a * s_rel[ci * CO + co];
        }
    }
#pragma unroll
    for (int ci = 0; ci < CI; ci++) {
        float hv = hr[ci];
#pragma unroll
        for (int co = 0; co < CO; co++) acc[co] += hv * s_root[ci * CO + co];
    }

    if (!valid) {
#pragma unroll
        for (int co = 0; co < CO; co++) acc[co] = 0.f;
    }

    if (valid) {
        float4* op = (float4*)(out + (size_t)n * CO);
#pragma unroll
        for (int i = 0; i < CO / 4; i++) {
            float4 v;
            v.x = acc[4 * i + 0]; v.y = acc[4 * i + 1]; v.z = acc[4 * i + 2]; v.w = acc[4 * i + 3];
            op[i] = v;
        }
    }

    // BN partial stats: per-wave butterfly reduce sum & sumsq, one atomic per wave per channel
#pragma unroll
    for (int co = 0; co < CO; co++) {
        float s = acc[co];
        float q = s * s;
#pragma unroll
        for (int off = 1; off < 64; off <<= 1) {
            s += __shfl_xor(s, off, 64);
            q += __shfl_xor(q, off, 64);
        }
        if ((threadIdx.x & 63) == 0) {
            atomicAdd(&stats[co], s);
            atomicAdd(&stats[64 + co], q);
        }
    }
}

// ---------------- BN finalize: scale/shift per channel ----------------
__global__ void k_bn_final(float* __restrict__ stats, const float* __restrict__ g, const float* __restrict__ be,
                           int CO, float invN) {
    int c = threadIdx.x;
    if (c < CO) {
        float mean = stats[c] * invN;
        float var = stats[64 + c] * invN - mean * mean;
        float sc = g[c] * rsqrtf(var + 1e-5f);
        stats[128 + c] = sc;
        stats[192 + c] = be[c] - mean * sc;
    }
}

// ---------------- BN apply + ELU, in place ----------------
template <int CO>
__global__ __launch_bounds__(256) void k_bn_elu(float* __restrict__ h, const float* __restrict__ stats, int N) {
    __shared__ float sc[CO], sh[CO];
    if (threadIdx.x < CO) {
        sc[threadIdx.x] = stats[128 + threadIdx.x];
        sh[threadIdx.x] = stats[192 + threadIdx.x];
    }
    __syncthreads();
    int total = N * (CO / 4);
    int i = blockIdx.x * 256 + threadIdx.x;
    if (i >= total) return;
    float4 v = ((float4*)h)[i];
    int cq = (i % (CO / 4)) * 4;
    v.x = v.x * sc[cq + 0] + sh[cq + 0];
    v.y = v.y * sc[cq + 1] + sh[cq + 1];
    v.z = v.z * sc[cq + 2] + sh[cq + 2];
    v.w = v.w * sc[cq + 3] + sh[cq + 3];
    v.x = v.x > 0.f ? v.x : expm1f(v.x);
    v.y = v.y > 0.f ? v.y : expm1f(v.y);
    v.z = v.z > 0.f ? v.z : expm1f(v.z);
    v.w = v.w > 0.f ? v.w : expm1f(v.w);
    ((float4*)h)[i] = v;
}

// ---------------- global mean pool (batch is sorted): run-length segmented reduce ----------------
__global__ __launch_bounds__(256) void k_pool(const float* __restrict__ h, const int* __restrict__ batch,
                                              float* __restrict__ pooled, float* __restrict__ cntg, int N) {
    int lane = threadIdx.x & 63;
    int wid = blockIdx.x * 4 + (threadIdx.x >> 6);
    int n0 = wid * 64;
    if (n0 >= N) return;
    int nmax = N - n0; if (nmax > 64) nmax = 64;
    int cur = batch[n0];
    float acc = 0.f;
    int run = 0;
    for (int k = 0; k < nmax; k++) {
        int g = batch[n0 + k];
        if (g != cur) {
            atomicAdd(&pooled[(size_t)cur * 64 + lane], acc);
            if (lane == 0) atomicAdd(&cntg[cur], (float)run);
            cur = g; acc = 0.f; run = 0;
        }
        acc += h[(size_t)(n0 + k) * 64 + lane];
        run++;
    }
    atomicAdd(&pooled[(size_t)cur * 64 + lane], acc);
    if (lane == 0) atomicAdd(&cntg[cur], (float)run);
}

// ---------------- head: mean-div, lin1+relu, lin2, log_softmax ----------------
__global__ __launch_bounds__(256) void k_head(const float* __restrict__ pooled, const float* __restrict__ cntg,
                                              const float* __restrict__ w1, const float* __restrict__ b1,
                                              const float* __restrict__ w2, const float* __restrict__ b2,
                                              float* __restrict__ out) {
    __shared__ float sw1[64 * 64];
    __shared__ float sw2[64 * 10];
    __shared__ float sb1[64];
    __shared__ float sb2[10];
    for (int i = threadIdx.x; i < 64 * 64; i += 256) sw1[i] = w1[i];
    for (int i = threadIdx.x; i < 64 * 10; i += 256) sw2[i] = w2[i];
    if (threadIdx.x < 64) sb1[threadIdx.x] = b1[threadIdx.x];
    if (threadIdx.x < 10) sb2[threadIdx.x] = b2[threadIdx.x];
    __syncthreads();
    int g = threadIdx.x;  // 256 threads == 256 graphs
    float rec = 1.0f / fmaxf(cntg[g], 1.0f);
    float p[64];
#pragma unroll
    for (int k = 0; k < 64; k++) p[k] = pooled[(size_t)g * 64 + k] * rec;
    float z[64];
#pragma unroll
    for (int j = 0; j < 64; j++) {
        float a = sb1[j];
#pragma unroll
        for (int k = 0; k < 64; k++) a += p[k] * sw1[k * 64 + j];
        z[j] = fmaxf(a, 0.f);
    }
    float lg[10];
#pragma unroll
    for (int j = 0; j < 10; j++) {
        float a = sb2[j];
#pragma unroll
        for (int k = 0; k < 64; k++) a += z[k] * sw2[k * 10 + j];
        lg[j] = a;
    }
    float m = -1e30f;
#pragma unroll
    for (int j = 0; j < 10; j++) m = fmaxf(m, lg[j]);
    float s = 0.f;
#pragma unroll
    for (int j = 0; j < 10; j++) s += expf(lg[j] - m);
    float lse = m + logf(s);
#pragma unroll
    for (int j = 0; j < 10; j++) out[(size_t)g * 10 + j] = lg[j] - lse;
}

extern "C" void kernel_launch(void* const* d_in, const int* in_sizes, int n_in,
                              void* d_out, int out_size, void* d_ws, size_t ws_size,
                              hipStream_t stream) {
    const float* x = (const float*)d_in[0];
    const int* ei = (const int*)d_in[1];
    const int* batch = (const int*)d_in[2];
    const int N = in_sizes[0] / 64;
    const int E = in_sizes[1] / 2;
    const int* src = ei;
    const int* dst = ei + E;

    const float* w_rel1 = (const float*)d_in[3];
    const float* w_root1 = (const float*)d_in[4];
    const float* b1 = (const float*)d_in[5];
    const float* g1 = (const float*)d_in[6];
    const float* be1 = (const float*)d_in[7];
    const float* w_rel2 = (const float*)d_in[8];
    const float* w_root2 = (const float*)d_in[9];
    const float* b2 = (const float*)d_in[10];
    const float* g2 = (const float*)d_in[11];
    const float* be2 = (const float*)d_in[12];
    const float* w_rel3 = (const float*)d_in[13];
    const float* w_root3 = (const float*)d_in[14];
    const float* b3 = (const float*)d_in[15];
    const float* g3 = (const float*)d_in[16];
    const float* be3 = (const float*)d_in[17];
    const float* w_rel4 = (const float*)d_in[18];
    const float* w_root4 = (const float*)d_in[19];
    const float* b4 = (const float*)d_in[20];
    const float* g4 = (const float*)d_in[21];
    const float* be4 = (const float*)d_in[22];
    const float* w_lin1 = (const float*)d_in[23];
    const float* b_lin1 = (const float*)d_in[24];
    const float* w_lin2 = (const float*)d_in[25];
    const float* b_lin2 = (const float*)d_in[26];

    char* ws = (char*)d_ws;
    size_t off = 0;
    auto alloc = [&](size_t bytes) { size_t o = off; off += (bytes + 255) & ~(size_t)255; return o; };
    int* cnt = (int*)(ws + alloc((size_t)N * 4));
    int* row_start = (int*)(ws + alloc((size_t)(N + 1) * 4));
    int* cursor = (int*)(ws + alloc((size_t)N * 4));
    int* bsum = (int*)(ws + alloc((size_t)512 * 4));
    int* csr = (int*)(ws + alloc((size_t)E * 4));
    float* agg = (float*)(ws + alloc((size_t)N * 32 * 4));
    float* y1 = (float*)(ws + alloc((size_t)N * 16 * 4));
    float* bufA = (float*)(ws + alloc((size_t)N * 64 * 4));
    float* bufB = (float*)(ws + alloc((size_t)N * 64 * 4));
    float* stats = (float*)(ws + alloc(4 * 256 * 4));
    float* pooled = (float*)(ws + alloc((size_t)(NGRAPHS * 64 + NGRAPHS) * 4));
    float* cntg = pooled + NGRAPHS * 64;

    hipMemsetAsync(cnt, 0, (size_t)N * 4, stream);
    hipMemsetAsync(stats, 0, 4 * 256 * 4, stream);
    hipMemsetAsync(pooled, 0, (size_t)(NGRAPHS * 64 + NGRAPHS) * 4, stream);

    const int ebl = (E + 255) / 256;
    const int nbl = (N + 255) / 256;
    const int NB = nbl;  // number of scan blocks (must be <= 512)
    const float invN = 1.0f / (float)N;
    const int gbl = (N + 3) / 4;  // gather: 4 waves per block, 1 wave per node

    // ---- CSR build ----
    k_degree<<<ebl, 256, 0, stream>>>(dst, cnt, E);
    k_scan1<<<NB, 256, 0, stream>>>(cnt, bsum, N);
    k_scan2<<<1, 512, 0, stream>>>(bsum, NB);
    k_scan3<<<NB, 256, 0, stream>>>(cnt, bsum, row_start, N);
    hipMemcpyAsync(cursor, row_start, (size_t)N * 4, hipMemcpyDeviceToDevice, stream);
    k_fill<<<ebl, 256, 0, stream>>>(src, dst, cursor, csr, E);

    // ---- Layer 1 (64 -> 16): matmul first, aggregate 16 channels ----
    k_mm_rel1<<<nbl, 256, 0, stream>>>(x, w_rel1, y1, N);
    k_gather<16><<<gbl, 256, 0, stream>>>(y1, row_start, csr, agg, N);
    k_node<64, 16, true><<<nbl, 256, 0, stream>>>(x, agg, nullptr, w_root1, b1, bufA, stats + 0, N);
    k_bn_final<<<1, 64, 0, stream>>>(stats + 0, g1, be1, 16, invN);
    k_bn_elu<16><<<(N * 4 + 255) / 256, 256, 0, stream>>>(bufA, stats + 0, N);

    // ---- Layer 2 (16 -> 32): aggregate input (16 ch) ----
    k_gather<16><<<gbl, 256, 0, stream>>>(bufA, row_start, csr, agg, N);
    k_node<16, 32, false><<<nbl, 256, 0, stream>>>(bufA, agg, w_rel2, w_root2, b2, bufB, stats + 256, N);
    k_bn_final<<<1, 64, 0, stream>>>(stats + 256, g2, be2, 32, invN);
    k_bn_elu<32><<<(N * 8 + 255) / 256, 256, 0, stream>>>(bufB, stats + 256, N);

    // ---- Layer 3 (32 -> 32) ----
    k_gather<32><<<gbl, 256, 0, stream>>>(bufB, row_start, csr, agg, N);
    k_node<32, 32, false><<<nbl, 256, 0, stream>>>(bufB, agg, w_rel3, w_root3, b3, bufA, stats + 512, N);
    k_bn_final<<<1, 64, 0, stream>>>(stats + 512, g3, be3, 32, invN);
    k_bn_elu<32><<<(N * 8 + 255) / 256, 256, 0, stream>>>(bufA, stats + 512, N);

    // ---- Layer 4 (32 -> 64) ----
    k_gather<32><<<gbl, 256, 0, stream>>>(bufA, row_start, csr, agg, N);
    k_node<32, 64, false><<<nbl, 256, 0, stream>>>(bufA, agg, w_rel4, w_root4, b4, bufB, stats + 768, N);
    k_bn_final<<<1, 64, 0, stream>>>(stats + 768, g4, be4, 64, invN);
    k_bn_elu<64><<<(N * 16 + 255) / 256, 256, 0, stream>>>(bufB, stats + 768, N);

    // ---- global mean pool + head ----
    int waves = (N + 63) / 64;
    k_pool<<<(waves + 3) / 4, 256, 0, stream>>>(bufB, batch, pooled, cntg, N);
    k_head<<<1, 256, 0, stream>>>(pooled, cntg, w_lin1, b_lin1, w_lin2, b_lin2, (float*)d_out);
}

// Round 3
// 1747.780 us; speedup vs baseline: 10.2449x; 1.7227x over previous
//
#include <hip/hip_runtime.h>
#include <hip/hip_bf16.h>
#include <math.h>

#define NGRAPHS 256

// ---------------- degree histogram ----------------
__global__ __launch_bounds__(256) void k_degree(const int* __restrict__ dst, int* __restrict__ cnt, int E) {
    int e = blockIdx.x * 256 + threadIdx.x;
    if (e < E) atomicAdd(&cnt[dst[e]], 1);
}

// ---------------- scan pass 1: per-block sums ----------------
__global__ __launch_bounds__(256) void k_scan1(const int* __restrict__ cnt, int* __restrict__ bsum, int N) {
    int i = blockIdx.x * 256 + threadIdx.x;
    int v = (i < N) ? cnt[i] : 0;
#pragma unroll
    for (int off = 1; off < 64; off <<= 1) v += __shfl_xor(v, off, 64);
    __shared__ int ws[4];
    if ((threadIdx.x & 63) == 0) ws[threadIdx.x >> 6] = v;
    __syncthreads();
    if (threadIdx.x == 0) bsum[blockIdx.x] = ws[0] + ws[1] + ws[2] + ws[3];
}

// ---------------- scan pass 2: exclusive scan of block sums (NB <= 512) ----------------
__global__ __launch_bounds__(512) void k_scan2(int* __restrict__ bsum, int NB) {
    __shared__ int s[512];
    int tid = threadIdx.x;
    int v = (tid < NB) ? bsum[tid] : 0;
    s[tid] = v;
    __syncthreads();
    for (int off = 1; off < 512; off <<= 1) {
        int t = (tid >= off) ? s[tid - off] : 0;
        __syncthreads();
        s[tid] += t;
        __syncthreads();
    }
    if (tid < NB) bsum[tid] = s[tid] - v;  // exclusive
}

// ---------------- scan pass 3: per-block exclusive scan + offset -> row_start ----------------
__global__ __launch_bounds__(256) void k_scan3(const int* __restrict__ cnt, const int* __restrict__ bsum,
                                               int* __restrict__ row_start, int N) {
    __shared__ int s[256];
    int tid = threadIdx.x;
    int i = blockIdx.x * 256 + tid;
    int v = (i < N) ? cnt[i] : 0;
    s[tid] = v;
    __syncthreads();
    for (int off = 1; off < 256; off <<= 1) {
        int t = (tid >= off) ? s[tid - off] : 0;
        __syncthreads();
        s[tid] += t;
        __syncthreads();
    }
    if (i < N) row_start[i] = bsum[blockIdx.x] + s[tid] - v;
    if (i == N - 1) row_start[N] = bsum[blockIdx.x] + s[tid];
}

// ---------------- CSR fill ----------------
__global__ __launch_bounds__(256) void k_fill(const int* __restrict__ src, const int* __restrict__ dst,
                                              int* __restrict__ cursor, int* __restrict__ csr, int E) {
    int e = blockIdx.x * 256 + threadIdx.x;
    if (e >= E) return;
    int d = dst[e];
    int p = atomicAdd(&cursor[d], 1);
    csr[p] = src[e];
}

// ---------------- layer-1 pre-matmul: y = x @ w_rel1 (N x 64 @ 64 x 16), weights scalar ----------------
__global__ __launch_bounds__(256) void k_mm_rel1(const float* __restrict__ x, const float* __restrict__ w,
                                                 float* __restrict__ y, int N) {
    int n = blockIdx.x * 256 + threadIdx.x;
    if (n >= N) return;
    float xr[64];
    const float4* xp = (const float4*)(x + (size_t)n * 64);
#pragma unroll
    for (int i = 0; i < 16; i++) {
        float4 v = xp[i];
        xr[4 * i + 0] = v.x; xr[4 * i + 1] = v.y; xr[4 * i + 2] = v.z; xr[4 * i + 3] = v.w;
    }
    float acc[16];
#pragma unroll
    for (int j = 0; j < 16; j++) acc[j] = 0.f;
#pragma unroll 4
    for (int ci = 0; ci < 64; ci++) {
        float xv = xr[ci];
#pragma unroll
        for (int j = 0; j < 16; j++) acc[j] += xv * w[ci * 16 + j];  // uniform idx -> s_load
    }
    float4* yp = (float4*)(y + (size_t)n * 16);
#pragma unroll
    for (int j = 0; j < 4; j++) {
        float4 v; v.x = acc[4 * j]; v.y = acc[4 * j + 1]; v.z = acc[4 * j + 2]; v.w = acc[4 * j + 3];
        yp[j] = v;
    }
}

// ---------------- gather-based mean aggregation: one wave per node ----------------
template <int C>
__global__ __launch_bounds__(256) void k_gather(const float* __restrict__ h, const int* __restrict__ row_start,
                                                const int* __restrict__ csr, float* __restrict__ agg, int N) {
    constexpr int EPP = 64 / C;  // edges per pass
    int lane = threadIdx.x & 63;
    int wid = blockIdx.x * 4 + (threadIdx.x >> 6);
    if (wid >= N) return;
    int r0 = row_start[wid];
    int deg = row_start[wid + 1] - r0;
    int c = lane & (C - 1);
    int es = lane / C;
    float acc = 0.f;
    for (int j = es; j < deg; j += EPP) {
        int s = csr[r0 + j];
        acc += h[(size_t)s * C + c];
    }
#pragma unroll
    for (int off = C; off < 64; off <<= 1) acc += __shfl_xor(acc, off, 64);
    if (lane < C) {
        float rec = 1.0f / (float)(deg > 0 ? deg : 1);
        agg[(size_t)wid * C + c] = acc * rec;
    }
}

// ---------------- node update: out = agg@w_rel + h@w_root + b (weights via scalar loads) ----------------
// PRE=true: agg already holds CO channels (pre-multiplied by w_rel): out = agg + h@w_root + b
template <int CI, int CO, bool PRE>
__global__ __launch_bounds__(256) void k_node(const float* __restrict__ h, const float* __restrict__ agg,
                                              const float* __restrict__ w_rel,
                                              const float* __restrict__ w_root, const float* __restrict__ bias,
                                              float* __restrict__ out, int N) {
    int n = blockIdx.x * 256 + threadIdx.x;
    if (n >= N) return;

    float hr[CI];
    {
        const float4* hp = (const float4*)(h + (size_t)n * CI);
#pragma unroll
        for (int i = 0; i < CI / 4; i++) {
            float4 v = hp[i];
            hr[4 * i + 0] = v.x; hr[4 * i + 1] = v.y; hr[4 * i + 2] = v.z; hr[4 * i + 3] = v.w;
        }
    }
    float ar[PRE ? 1 : CI];
    if (!PRE) {
        const float4* mp = (const float4*)(agg + (size_t)n * CI);
#pragma unroll
        for (int i = 0; i < CI / 4; i++) {
            float4 v = mp[i];
            ar[4 * i + 0] = v.x; ar[4 * i + 1] = v.y; ar[4 * i + 2] = v.z; ar[4 * i + 3] = v.w;
        }
    }

    // chunk CO to bound register pressure (only CI=32,CO=64 needs splitting)
    constexpr int CHUNK = (CI + CO > 96) ? 32 : CO;
#pragma unroll 1
    for (int c0 = 0; c0 < CO; c0 += CHUNK) {
        float acc[CHUNK];
        if (PRE) {
            const float4* mp = (const float4*)(agg + (size_t)n * CO + c0);
#pragma unroll
            for (int i = 0; i < CHUNK / 4; i++) {
                float4 v = mp[i];
                acc[4 * i + 0] = v.x + bias[c0 + 4 * i + 0];
                acc[4 * i + 1] = v.y + bias[c0 + 4 * i + 1];
                acc[4 * i + 2] = v.z + bias[c0 + 4 * i + 2];
                acc[4 * i + 3] = v.w + bias[c0 + 4 * i + 3];
            }
        } else {
#pragma unroll
            for (int j = 0; j < CHUNK; j++) acc[j] = bias[c0 + j];
        }
#pragma unroll 2
        for (int ci = 0; ci < CI; ci++) {
            float hv = hr[ci];
            if (!PRE) {
                float a = ar[ci];
#pragma unroll
                for (int j = 0; j < CHUNK; j++)
                    acc[j] += a * w_rel[ci * CO + c0 + j] + hv * w_root[ci * CO + c0 + j];
            } else {
#pragma unroll
                for (int j = 0; j < CHUNK; j++)
                    acc[j] += hv * w_root[ci * CO + c0 + j];
            }
        }
        float4* op = (float4*)(out + (size_t)n * CO + c0);
#pragma unroll
        for (int i = 0; i < CHUNK / 4; i++) {
            float4 v;
            v.x = acc[4 * i + 0]; v.y = acc[4 * i + 1]; v.z = acc[4 * i + 2]; v.w = acc[4 * i + 3];
            op[i] = v;
        }
    }
}

// ---------------- BN stats: grid-stride, per-thread fixed column quad, wave reduce, atomics ----------------
template <int CO>
__global__ __launch_bounds__(256) void k_stats(const float* __restrict__ h, float* __restrict__ stats, int N) {
    constexpr int QPR = CO / 4;  // float4 quads per row
    int total = N * QPR;
    float s0 = 0, s1 = 0, s2 = 0, s3 = 0, q0 = 0, q1 = 0, q2 = 0, q3 = 0;
    int idx = blockIdx.x * 256 + threadIdx.x;
    // stride (gridDim*256) is a multiple of QPR, so each thread's column quad is fixed
    for (int i = idx; i < total; i += gridDim.x * 256) {
        float4 v = ((const float4*)h)[i];
        s0 += v.x; q0 += v.x * v.x;
        s1 += v.y; q1 += v.y * v.y;
        s2 += v.z; q2 += v.z * v.z;
        s3 += v.w; q3 += v.w * v.w;
    }
#pragma unroll
    for (int off = QPR; off < 64; off <<= 1) {
        s0 += __shfl_xor(s0, off, 64); q0 += __shfl_xor(q0, off, 64);
        s1 += __shfl_xor(s1, off, 64); q1 += __shfl_xor(q1, off, 64);
        s2 += __shfl_xor(s2, off, 64); q2 += __shfl_xor(q2, off, 64);
        s3 += __shfl_xor(s3, off, 64); q3 += __shfl_xor(q3, off, 64);
    }
    int lane = threadIdx.x & 63;
    if (lane < QPR) {
        int cq = lane * 4;
        atomicAdd(&stats[cq + 0], s0); atomicAdd(&stats[64 + cq + 0], q0);
        atomicAdd(&stats[cq + 1], s1); atomicAdd(&stats[64 + cq + 1], q1);
        atomicAdd(&stats[cq + 2], s2); atomicAdd(&stats[64 + cq + 2], q2);
        atomicAdd(&stats[cq + 3], s3); atomicAdd(&stats[64 + cq + 3], q3);
    }
}

// ---------------- BN finalize: scale/shift per channel ----------------
__global__ void k_bn_final(float* __restrict__ stats, const float* __restrict__ g, const float* __restrict__ be,
                           int CO, float invN) {
    int c = threadIdx.x;
    if (c < CO) {
        float mean = stats[c] * invN;
        float var = stats[64 + c] * invN - mean * mean;
        float sc = g[c] * rsqrtf(var + 1e-5f);
        stats[128 + c] = sc;
        stats[192 + c] = be[c] - mean * sc;
    }
}

// ---------------- BN apply + ELU, in place ----------------
template <int CO>
__global__ __launch_bounds__(256) void k_bn_elu(float* __restrict__ h, const float* __restrict__ stats, int N) {
    int total = N * (CO / 4);
    int i = blockIdx.x * 256 + threadIdx.x;
    if (i >= total) return;
    float4 v = ((float4*)h)[i];
    int cq = (i % (CO / 4)) * 4;
    v.x = v.x * stats[128 + cq + 0] + stats[192 + cq + 0];
    v.y = v.y * stats[128 + cq + 1] + stats[192 + cq + 1];
    v.z = v.z * stats[128 + cq + 2] + stats[192 + cq + 2];
    v.w = v.w * stats[128 + cq + 3] + stats[192 + cq + 3];
    v.x = v.x > 0.f ? v.x : expm1f(v.x);
    v.y = v.y > 0.f ? v.y : expm1f(v.y);
    v.z = v.z > 0.f ? v.z : expm1f(v.z);
    v.w = v.w > 0.f ? v.w : expm1f(v.w);
    ((float4*)h)[i] = v;
}

// ---------------- global mean pool (batch is sorted): run-length segmented reduce ----------------
__global__ __launch_bounds__(256) void k_pool(const float* __restrict__ h, const int* __restrict__ batch,
                                              float* __restrict__ pooled, float* __restrict__ cntg, int N) {
    int lane = threadIdx.x & 63;
    int wid = blockIdx.x * 4 + (threadIdx.x >> 6);
    int n0 = wid * 64;
    if (n0 >= N) return;
    int nmax = N - n0; if (nmax > 64) nmax = 64;
    int cur = batch[n0];
    float acc = 0.f;
    int run = 0;
    for (int k = 0; k < nmax; k++) {
        int g = batch[n0 + k];
        if (g != cur) {
            atomicAdd(&pooled[(size_t)cur * 64 + lane], acc);
            if (lane == 0) atomicAdd(&cntg[cur], (float)run);
            cur = g; acc = 0.f; run = 0;
        }
        acc += h[(size_t)(n0 + k) * 64 + lane];
        run++;
    }
    atomicAdd(&pooled[(size_t)cur * 64 + lane], acc);
    if (lane == 0) atomicAdd(&cntg[cur], (float)run);
}

// ---------------- head: mean-div, lin1+relu fused into lin2 accumulation, log_softmax ----------------
__global__ __launch_bounds__(256) void k_head(const float* __restrict__ pooled, const float* __restrict__ cntg,
                                              const float* __restrict__ w1, const float* __restrict__ b1,
                                              const float* __restrict__ w2, const float* __restrict__ b2,
                                              float* __restrict__ out) {
    int g = threadIdx.x;  // 256 threads == 256 graphs
    float rec = 1.0f / fmaxf(cntg[g], 1.0f);
    float p[64];
    {
        const float4* pp = (const float4*)(pooled + (size_t)g * 64);
#pragma unroll
        for (int i = 0; i < 16; i++) {
            float4 v = pp[i];
            p[4 * i + 0] = v.x * rec; p[4 * i + 1] = v.y * rec;
            p[4 * i + 2] = v.z * rec; p[4 * i + 3] = v.w * rec;
        }
    }
    float lg[10];
#pragma unroll
    for (int t = 0; t < 10; t++) lg[t] = b2[t];
#pragma unroll 1
    for (int j = 0; j < 64; j++) {
        float a = b1[j];
#pragma unroll
        for (int k = 0; k < 64; k++) a += p[k] * w1[k * 64 + j];  // uniform -> s_load
        a = fmaxf(a, 0.f);
#pragma unroll
        for (int t = 0; t < 10; t++) lg[t] += a * w2[j * 10 + t];
    }
    float m = -1e30f;
#pragma unroll
    for (int t = 0; t < 10; t++) m = fmaxf(m, lg[t]);
    float s = 0.f;
#pragma unroll
    for (int t = 0; t < 10; t++) s += expf(lg[t] - m);
    float lse = m + logf(s);
#pragma unroll
    for (int t = 0; t < 10; t++) out[(size_t)g * 10 + t] = lg[t] - lse;
}

extern "C" void kernel_launch(void* const* d_in, const int* in_sizes, int n_in,
                              void* d_out, int out_size, void* d_ws, size_t ws_size,
                              hipStream_t stream) {
    const float* x = (const float*)d_in[0];
    const int* ei = (const int*)d_in[1];
    const int* batch = (const int*)d_in[2];
    const int N = in_sizes[0] / 64;
    const int E = in_sizes[1] / 2;
    const int* src = ei;
    const int* dst = ei + E;

    const float* w_rel1 = (const float*)d_in[3];
    const float* w_root1 = (const float*)d_in[4];
    const float* b1 = (const float*)d_in[5];
    const float* g1 = (const float*)d_in[6];
    const float* be1 = (const float*)d_in[7];
    const float* w_rel2 = (const float*)d_in[8];
    const float* w_root2 = (const float*)d_in[9];
    const float* b2 = (const float*)d_in[10];
    const float* g2 = (const float*)d_in[11];
    const float* be2 = (const float*)d_in[12];
    const float* w_rel3 = (const float*)d_in[13];
    const float* w_root3 = (const float*)d_in[14];
    const float* b3 = (const float*)d_in[15];
    const float* g3 = (const float*)d_in[16];
    const float* be3 = (const float*)d_in[17];
    const float* w_rel4 = (const float*)d_in[18];
    const float* w_root4 = (const float*)d_in[19];
    const float* b4 = (const float*)d_in[20];
    const float* g4 = (const float*)d_in[21];
    const float* be4 = (const float*)d_in[22];
    const float* w_lin1 = (const float*)d_in[23];
    const float* b_lin1 = (const float*)d_in[24];
    const float* w_lin2 = (const float*)d_in[25];
    const float* b_lin2 = (const float*)d_in[26];

    char* ws = (char*)d_ws;
    size_t off = 0;
    auto alloc = [&](size_t bytes) { size_t o = off; off += (bytes + 255) & ~(size_t)255; return o; };
    int* cnt = (int*)(ws + alloc((size_t)N * 4));
    int* row_start = (int*)(ws + alloc((size_t)(N + 1) * 4));
    int* cursor = (int*)(ws + alloc((size_t)N * 4));
    int* bsum = (int*)(ws + alloc((size_t)512 * 4));
    int* csr = (int*)(ws + alloc((size_t)E * 4));
    float* agg = (float*)(ws + alloc((size_t)N * 32 * 4));
    float* y1 = (float*)(ws + alloc((size_t)N * 16 * 4));
    float* bufA = (float*)(ws + alloc((size_t)N * 64 * 4));
    float* bufB = (float*)(ws + alloc((size_t)N * 64 * 4));
    float* stats = (float*)(ws + alloc(4 * 256 * 4));
    float* pooled = (float*)(ws + alloc((size_t)(NGRAPHS * 64 + NGRAPHS) * 4));
    float* cntg = pooled + NGRAPHS * 64;

    hipMemsetAsync(cnt, 0, (size_t)N * 4, stream);
    hipMemsetAsync(stats, 0, 4 * 256 * 4, stream);
    hipMemsetAsync(pooled, 0, (size_t)(NGRAPHS * 64 + NGRAPHS) * 4, stream);

    const int ebl = (E + 255) / 256;
    const int nbl = (N + 255) / 256;
    const int NB = nbl;  // scan blocks (<=512)
    const float invN = 1.0f / (float)N;
    const int gbl = (N + 3) / 4;  // gather: 4 waves/block, 1 wave/node
    const int sbl = 512;          // stats grid

    // ---- CSR build ----
    k_degree<<<ebl, 256, 0, stream>>>(dst, cnt, E);
    k_scan1<<<NB, 256, 0, stream>>>(cnt, bsum, N);
    k_scan2<<<1, 512, 0, stream>>>(bsum, NB);
    k_scan3<<<NB, 256, 0, stream>>>(cnt, bsum, row_start, N);
    hipMemcpyAsync(cursor, row_start, (size_t)N * 4, hipMemcpyDeviceToDevice, stream);
    k_fill<<<ebl, 256, 0, stream>>>(src, dst, cursor, csr, E);

    // ---- Layer 1 (64 -> 16): matmul first, aggregate 16 channels ----
    k_mm_rel1<<<nbl, 256, 0, stream>>>(x, w_rel1, y1, N);
    k_gather<16><<<gbl, 256, 0, stream>>>(y1, row_start, csr, agg, N);
    k_node<64, 16, true><<<nbl, 256, 0, stream>>>(x, agg, nullptr, w_root1, b1, bufA, N);
    k_stats<16><<<sbl, 256, 0, stream>>>(bufA, stats + 0, N);
    k_bn_final<<<1, 64, 0, stream>>>(stats + 0, g1, be1, 16, invN);
    k_bn_elu<16><<<(N * 4 + 255) / 256, 256, 0, stream>>>(bufA, stats + 0, N);

    // ---- Layer 2 (16 -> 32) ----
    k_gather<16><<<gbl, 256, 0, stream>>>(bufA, row_start, csr, agg, N);
    k_node<16, 32, false><<<nbl, 256, 0, stream>>>(bufA, agg, w_rel2, w_root2, b2, bufB, N);
    k_stats<32><<<sbl, 256, 0, stream>>>(bufB, stats + 256, N);
    k_bn_final<<<1, 64, 0, stream>>>(stats + 256, g2, be2, 32, invN);
    k_bn_elu<32><<<(N * 8 + 255) / 256, 256, 0, stream>>>(bufB, stats + 256, N);

    // ---- Layer 3 (32 -> 32) ----
    k_gather<32><<<gbl, 256, 0, stream>>>(bufB, row_start, csr, agg, N);
    k_node<32, 32, false><<<nbl, 256, 0, stream>>>(bufB, agg, w_rel3, w_root3, b3, bufA, N);
    k_stats<32><<<sbl, 256, 0, stream>>>(bufA, stats + 512, N);
    k_bn_final<<<1, 64, 0, stream>>>(stats + 512, g3, be3, 32, invN);
    k_bn_elu<32><<<(N * 8 + 255) / 256, 256, 0, stream>>>(bufA, stats + 512, N);

    // ---- Layer 4 (32 -> 64) ----
    k_gather<32><<<gbl, 256, 0, stream>>>(bufA, row_start, csr, agg, N);
    k_node<32, 64, false><<<nbl, 256, 0, stream>>>(bufA, agg, w_rel4, w_root4, b4, bufB, N);
    k_stats<64><<<sbl, 256, 0, stream>>>(bufB, stats + 768, N);
    k_bn_final<<<1, 64, 0, stream>>>(stats + 768, g4, be4, 64, invN);
    k_bn_elu<64><<<(N * 16 + 255) / 256, 256, 0, stream>>>(bufB, stats + 768, N);

    // ---- global mean pool + head ----
    int waves = (N + 63) / 64;
    k_pool<<<(waves + 3) / 4, 256, 0, stream>>>(bufB, batch, pooled, cntg, N);
    k_head<<<1, 256, 0, stream>>>(pooled, cntg, w_lin1, b_lin1, w_lin2, b_lin2, (float*)d_out);
}

// Round 4
// 1518.128 us; speedup vs baseline: 11.7947x; 1.1513x over previous
//
#include <hip/hip_runtime.h>
#include <hip/hip_bf16.h>
#include <math.h>

#define NGRAPHS 256

// ---------------- degree histogram ----------------
__global__ __launch_bounds__(256) void k_degree(const int* __restrict__ dst, int* __restrict__ cnt, int E) {
    int e = blockIdx.x * 256 + threadIdx.x;
    if (e < E) {
        int d = __builtin_nontemporal_load(dst + e);
        atomicAdd(&cnt[d], 1);
    }
}

// ---------------- scan pass 1: per-block sums ----------------
__global__ __launch_bounds__(256) void k_scan1(const int* __restrict__ cnt, int* __restrict__ bsum, int N) {
    int i = blockIdx.x * 256 + threadIdx.x;
    int v = (i < N) ? cnt[i] : 0;
#pragma unroll
    for (int off = 1; off < 64; off <<= 1) v += __shfl_xor(v, off, 64);
    __shared__ int ws[4];
    if ((threadIdx.x & 63) == 0) ws[threadIdx.x >> 6] = v;
    __syncthreads();
    if (threadIdx.x == 0) bsum[blockIdx.x] = ws[0] + ws[1] + ws[2] + ws[3];
}

// ---------------- scan pass 2: exclusive scan of block sums (NB <= 512) ----------------
__global__ __launch_bounds__(512) void k_scan2(int* __restrict__ bsum, int NB) {
    __shared__ int s[512];
    int tid = threadIdx.x;
    int v = (tid < NB) ? bsum[tid] : 0;
    s[tid] = v;
    __syncthreads();
    for (int off = 1; off < 512; off <<= 1) {
        int t = (tid >= off) ? s[tid - off] : 0;
        __syncthreads();
        s[tid] += t;
        __syncthreads();
    }
    if (tid < NB) bsum[tid] = s[tid] - v;  // exclusive
}

// ---------------- scan pass 3: per-block exclusive scan -> row_start AND cursor ----------------
__global__ __launch_bounds__(256) void k_scan3(const int* __restrict__ cnt, const int* __restrict__ bsum,
                                               int* __restrict__ row_start, int* __restrict__ cursor, int N) {
    __shared__ int s[256];
    int tid = threadIdx.x;
    int i = blockIdx.x * 256 + tid;
    int v = (i < N) ? cnt[i] : 0;
    s[tid] = v;
    __syncthreads();
    for (int off = 1; off < 256; off <<= 1) {
        int t = (tid >= off) ? s[tid - off] : 0;
        __syncthreads();
        s[tid] += t;
        __syncthreads();
    }
    if (i < N) {
        int v0 = bsum[blockIdx.x] + s[tid] - v;
        row_start[i] = v0;
        cursor[i] = v0;
    }
    if (i == N - 1) row_start[N] = bsum[blockIdx.x] + s[tid];
}

// ---------------- CSR fill: NT edge reads (keep L2 for csr write coalescing) ----------------
__global__ __launch_bounds__(256) void k_fill(const int* __restrict__ src, const int* __restrict__ dst,
                                              int* __restrict__ cursor, int* __restrict__ csr, int E) {
    int e = blockIdx.x * 256 + threadIdx.x;
    if (e >= E) return;
    int d = __builtin_nontemporal_load(dst + e);
    int sv = __builtin_nontemporal_load(src + e);
    int p = atomicAdd(&cursor[d], 1);
    csr[p] = sv;
}

// ---------------- layer-1 pre-matmul: y = x @ w_rel1 (N x 64 @ 64 x 16), weights scalar ----------------
__global__ __launch_bounds__(256) void k_mm_rel1(const float* __restrict__ x, const float* __restrict__ w,
                                                 float* __restrict__ y, int N) {
    int n = blockIdx.x * 256 + threadIdx.x;
    if (n >= N) return;
    float xr[64];
    const float4* xp = (const float4*)(x + (size_t)n * 64);
#pragma unroll
    for (int i = 0; i < 16; i++) {
        float4 v = xp[i];
        xr[4 * i + 0] = v.x; xr[4 * i + 1] = v.y; xr[4 * i + 2] = v.z; xr[4 * i + 3] = v.w;
    }
    float acc[16];
#pragma unroll
    for (int j = 0; j < 16; j++) acc[j] = 0.f;
#pragma unroll 4
    for (int ci = 0; ci < 64; ci++) {
        float xv = xr[ci];
#pragma unroll
        for (int j = 0; j < 16; j++) acc[j] += xv * w[ci * 16 + j];  // uniform idx -> s_load
    }
    float4* yp = (float4*)(y + (size_t)n * 16);
#pragma unroll
    for (int j = 0; j < 4; j++) {
        float4 v; v.x = acc[4 * j]; v.y = acc[4 * j + 1]; v.z = acc[4 * j + 2]; v.w = acc[4 * j + 3];
        yp[j] = v;
    }
}

// ---------------- gather-based mean aggregation: one wave per node, float4 row quads ----------------
// LPR = C/4 lanes cover one row; EPP = 64/LPR rows per pass; unroll U so 32 edges in flight.
template <int C>
__global__ __launch_bounds__(256) void k_gather(const float* __restrict__ h, const int* __restrict__ row_start,
                                                const int* __restrict__ csr, float* __restrict__ agg, int N) {
    constexpr int LPR = C / 4;
    constexpr int EPP = 64 / LPR;
    constexpr int U = (EPP >= 16) ? 2 : 4;  // 32 edges in flight
    int lane = threadIdx.x & 63;
    int wid = blockIdx.x * 4 + (threadIdx.x >> 6);
    if (wid >= N) return;
    int r0 = row_start[wid];
    int deg = row_start[wid + 1] - r0;
    int es = lane / LPR;
    int cq = (lane % LPR) * 4;
    float ax = 0.f, ay = 0.f, az = 0.f, aw = 0.f;
    int j = es;
    for (; j + (U - 1) * EPP < deg; j += U * EPP) {
        int s[U];
#pragma unroll
        for (int u = 0; u < U; u++) s[u] = __builtin_nontemporal_load(&csr[r0 + j + u * EPP]);
        float4 v[U];
#pragma unroll
        for (int u = 0; u < U; u++) v[u] = *(const float4*)(h + (size_t)s[u] * C + cq);
#pragma unroll
        for (int u = 0; u < U; u++) { ax += v[u].x; ay += v[u].y; az += v[u].z; aw += v[u].w; }
    }
    for (; j < deg; j += EPP) {
        int sv = __builtin_nontemporal_load(&csr[r0 + j]);
        float4 v = *(const float4*)(h + (size_t)sv * C + cq);
        ax += v.x; ay += v.y; az += v.z; aw += v.w;
    }
#pragma unroll
    for (int off = LPR; off < 64; off <<= 1) {
        ax += __shfl_xor(ax, off, 64);
        ay += __shfl_xor(ay, off, 64);
        az += __shfl_xor(az, off, 64);
        aw += __shfl_xor(aw, off, 64);
    }
    if (lane < LPR) {
        float rec = 1.0f / (float)(deg > 0 ? deg : 1);
        float4 o; o.x = ax * rec; o.y = ay * rec; o.z = az * rec; o.w = aw * rec;
        *(float4*)(agg + (size_t)wid * C + cq) = o;
    }
}

// ---------------- node update: out = agg@w_rel + h@w_root + b (weights via scalar loads) ----------------
template <int CI, int CO, bool PRE>
__global__ __launch_bounds__(256) void k_node(const float* __restrict__ h, const float* __restrict__ agg,
                                              const float* __restrict__ w_rel,
                                              const float* __restrict__ w_root, const float* __restrict__ bias,
                                              float* __restrict__ out, int N) {
    int n = blockIdx.x * 256 + threadIdx.x;
    if (n >= N) return;

    float hr[CI];
    {
        const float4* hp = (const float4*)(h + (size_t)n * CI);
#pragma unroll
        for (int i = 0; i < CI / 4; i++) {
            float4 v = hp[i];
            hr[4 * i + 0] = v.x; hr[4 * i + 1] = v.y; hr[4 * i + 2] = v.z; hr[4 * i + 3] = v.w;
        }
    }
    float ar[PRE ? 1 : CI];
    if (!PRE) {
        const float4* mp = (const float4*)(agg + (size_t)n * CI);
#pragma unroll
        for (int i = 0; i < CI / 4; i++) {
            float4 v = mp[i];
            ar[4 * i + 0] = v.x; ar[4 * i + 1] = v.y; ar[4 * i + 2] = v.z; ar[4 * i + 3] = v.w;
        }
    }

    constexpr int CHUNK = (CI + CO > 96) ? 32 : CO;
#pragma unroll 1
    for (int c0 = 0; c0 < CO; c0 += CHUNK) {
        float acc[CHUNK];
        if (PRE) {
            const float4* mp = (const float4*)(agg + (size_t)n * CO + c0);
#pragma unroll
            for (int i = 0; i < CHUNK / 4; i++) {
                float4 v = mp[i];
                acc[4 * i + 0] = v.x + bias[c0 + 4 * i + 0];
                acc[4 * i + 1] = v.y + bias[c0 + 4 * i + 1];
                acc[4 * i + 2] = v.z + bias[c0 + 4 * i + 2];
                acc[4 * i + 3] = v.w + bias[c0 + 4 * i + 3];
            }
        } else {
#pragma unroll
            for (int j = 0; j < CHUNK; j++) acc[j] = bias[c0 + j];
        }
#pragma unroll 2
        for (int ci = 0; ci < CI; ci++) {
            float hv = hr[ci];
            if (!PRE) {
                float a = ar[ci];
#pragma unroll
                for (int j = 0; j < CHUNK; j++)
                    acc[j] += a * w_rel[ci * CO + c0 + j] + hv * w_root[ci * CO + c0 + j];
            } else {
#pragma unroll
                for (int j = 0; j < CHUNK; j++)
                    acc[j] += hv * w_root[ci * CO + c0 + j];
            }
        }
        float4* op = (float4*)(out + (size_t)n * CO + c0);
#pragma unroll
        for (int i = 0; i < CHUNK / 4; i++) {
            float4 v;
            v.x = acc[4 * i + 0]; v.y = acc[4 * i + 1]; v.z = acc[4 * i + 2]; v.w = acc[4 * i + 3];
            op[i] = v;
        }
    }
}

// ---------------- BN stats: grid-stride, fixed column quad per thread, wave reduce, atomics ----------------
template <int CO>
__global__ __launch_bounds__(256) void k_stats(const float* __restrict__ h, float* __restrict__ stats, int N) {
    constexpr int QPR = CO / 4;
    int total = N * QPR;
    float s0 = 0, s1 = 0, s2 = 0, s3 = 0, q0 = 0, q1 = 0, q2 = 0, q3 = 0;
    int idx = blockIdx.x * 256 + threadIdx.x;
    for (int i = idx; i < total; i += gridDim.x * 256) {
        float4 v = ((const float4*)h)[i];
        s0 += v.x; q0 += v.x * v.x;
        s1 += v.y; q1 += v.y * v.y;
        s2 += v.z; q2 += v.z * v.z;
        s3 += v.w; q3 += v.w * v.w;
    }
#pragma unroll
    for (int off = QPR; off < 64; off <<= 1) {
        s0 += __shfl_xor(s0, off, 64); q0 += __shfl_xor(q0, off, 64);
        s1 += __shfl_xor(s1, off, 64); q1 += __shfl_xor(q1, off, 64);
        s2 += __shfl_xor(s2, off, 64); q2 += __shfl_xor(q2, off, 64);
        s3 += __shfl_xor(s3, off, 64); q3 += __shfl_xor(q3, off, 64);
    }
    int lane = threadIdx.x & 63;
    if (lane < QPR) {
        int cq = lane * 4;
        atomicAdd(&stats[cq + 0], s0); atomicAdd(&stats[64 + cq + 0], q0);
        atomicAdd(&stats[cq + 1], s1); atomicAdd(&stats[64 + cq + 1], q1);
        atomicAdd(&stats[cq + 2], s2); atomicAdd(&stats[64 + cq + 2], q2);
        atomicAdd(&stats[cq + 3], s3); atomicAdd(&stats[64 + cq + 3], q3);
    }
}

// ---------------- BN finalize folded into apply + ELU, in place ----------------
template <int CO>
__global__ __launch_bounds__(256) void k_bn_elu(float* __restrict__ h, const float* __restrict__ stats,
                                                const float* __restrict__ g, const float* __restrict__ be,
                                                int N, float invN) {
    __shared__ float sc[CO], sh[CO];
    if (threadIdx.x < CO) {
        int c = threadIdx.x;
        float mean = stats[c] * invN;
        float var = stats[64 + c] * invN - mean * mean;
        float s = g[c] * rsqrtf(var + 1e-5f);
        sc[c] = s;
        sh[c] = be[c] - mean * s;
    }
    __syncthreads();
    int total = N * (CO / 4);
    int i = blockIdx.x * 256 + threadIdx.x;
    if (i >= total) return;
    float4 v = ((float4*)h)[i];
    int cq = (i % (CO / 4)) * 4;
    v.x = v.x * sc[cq + 0] + sh[cq + 0];
    v.y = v.y * sc[cq + 1] + sh[cq + 1];
    v.z = v.z * sc[cq + 2] + sh[cq + 2];
    v.w = v.w * sc[cq + 3] + sh[cq + 3];
    v.x = v.x > 0.f ? v.x : expm1f(v.x);
    v.y = v.y > 0.f ? v.y : expm1f(v.y);
    v.z = v.z > 0.f ? v.z : expm1f(v.z);
    v.w = v.w > 0.f ? v.w : expm1f(v.w);
    ((float4*)h)[i] = v;
}

// ---------------- global mean pool (batch is sorted): run-length segmented reduce ----------------
__global__ __launch_bounds__(256) void k_pool(const float* __restrict__ h, const int* __restrict__ batch,
                                              float* __restrict__ pooled, float* __restrict__ cntg, int N) {
    int lane = threadIdx.x & 63;
    int wid = blockIdx.x * 4 + (threadIdx.x >> 6);
    int n0 = wid * 64;
    if (n0 >= N) return;
    int nmax = N - n0; if (nmax > 64) nmax = 64;
    int cur = batch[n0];
    float acc = 0.f;
    int run = 0;
    for (int k = 0; k < nmax; k++) {
        int g = batch[n0 + k];
        if (g != cur) {
            atomicAdd(&pooled[(size_t)cur * 64 + lane], acc);
            if (lane == 0) atomicAdd(&cntg[cur], (float)run);
            cur = g; acc = 0.f; run = 0;
        }
        acc += h[(size_t)(n0 + k) * 64 + lane];
        run++;
    }
    atomicAdd(&pooled[(size_t)cur * 64 + lane], acc);
    if (lane == 0) atomicAdd(&cntg[cur], (float)run);
}

// ---------------- head ----------------
__global__ __launch_bounds__(256) void k_head(const float* __restrict__ pooled, const float* __restrict__ cntg,
                                              const float* __restrict__ w1, const float* __restrict__ b1,
                                              const float* __restrict__ w2, const float* __restrict__ b2,
                                              float* __restrict__ out) {
    int g = threadIdx.x;  // 256 threads == 256 graphs
    float rec = 1.0f / fmaxf(cntg[g], 1.0f);
    float p[64];
    {
        const float4* pp = (const float4*)(pooled + (size_t)g * 64);
#pragma unroll
        for (int i = 0; i < 16; i++) {
            float4 v = pp[i];
            p[4 * i + 0] = v.x * rec; p[4 * i + 1] = v.y * rec;
            p[4 * i + 2] = v.z * rec; p[4 * i + 3] = v.w * rec;
        }
    }
    float lg[10];
#pragma unroll
    for (int t = 0; t < 10; t++) lg[t] = b2[t];
#pragma unroll 1
    for (int j = 0; j < 64; j++) {
        float a = b1[j];
#pragma unroll
        for (int k = 0; k < 64; k++) a += p[k] * w1[k * 64 + j];  // uniform -> s_load
        a = fmaxf(a, 0.f);
#pragma unroll
        for (int t = 0; t < 10; t++) lg[t] += a * w2[j * 10 + t];
    }
    float m = -1e30f;
#pragma unroll
    for (int t = 0; t < 10; t++) m = fmaxf(m, lg[t]);
    float s = 0.f;
#pragma unroll
    for (int t = 0; t < 10; t++) s += expf(lg[t] - m);
    float lse = m + logf(s);
#pragma unroll
    for (int t = 0; t < 10; t++) out[(size_t)g * 10 + t] = lg[t] - lse;
}

extern "C" void kernel_launch(void* const* d_in, const int* in_sizes, int n_in,
                              void* d_out, int out_size, void* d_ws, size_t ws_size,
                              hipStream_t stream) {
    const float* x = (const float*)d_in[0];
    const int* ei = (const int*)d_in[1];
    const int* batch = (const int*)d_in[2];
    const int N = in_sizes[0] / 64;
    const int E = in_sizes[1] / 2;
    const int* src = ei;
    const int* dst = ei + E;

    const float* w_rel1 = (const float*)d_in[3];
    const float* w_root1 = (const float*)d_in[4];
    const float* b1 = (const float*)d_in[5];
    const float* g1 = (const float*)d_in[6];
    const float* be1 = (const float*)d_in[7];
    const float* w_rel2 = (const float*)d_in[8];
    const float* w_root2 = (const float*)d_in[9];
    const float* b2 = (const float*)d_in[10];
    const float* g2 = (const float*)d_in[11];
    const float* be2 = (const float*)d_in[12];
    const float* w_rel3 = (const float*)d_in[13];
    const float* w_root3 = (const float*)d_in[14];
    const float* b3 = (const float*)d_in[15];
    const float* g3 = (const float*)d_in[16];
    const float* be3 = (const float*)d_in[17];
    const float* w_rel4 = (const float*)d_in[18];
    const float* w_root4 = (const float*)d_in[19];
    const float* b4 = (const float*)d_in[20];
    const float* g4 = (const float*)d_in[21];
    const float* be4 = (const float*)d_in[22];
    const float* w_lin1 = (const float*)d_in[23];
    const float* b_lin1 = (const float*)d_in[24];
    const float* w_lin2 = (const float*)d_in[25];
    const float* b_lin2 = (const float*)d_in[26];

    char* ws = (char*)d_ws;
    size_t off = 0;
    auto alloc = [&](size_t bytes) { size_t o = off; off += (bytes + 255) & ~(size_t)255; return o; };
    int* cnt = (int*)(ws + alloc((size_t)N * 4));
    int* row_start = (int*)(ws + alloc((size_t)(N + 1) * 4));
    int* cursor = (int*)(ws + alloc((size_t)N * 4));
    int* bsum = (int*)(ws + alloc((size_t)512 * 4));
    int* csr = (int*)(ws + alloc((size_t)E * 4));
    float* agg = (float*)(ws + alloc((size_t)N * 32 * 4));
    float* y1 = (float*)(ws + alloc((size_t)N * 16 * 4));
    float* bufA = (float*)(ws + alloc((size_t)N * 64 * 4));
    float* bufB = (float*)(ws + alloc((size_t)N * 64 * 4));
    float* stats = (float*)(ws + alloc(4 * 256 * 4));
    float* pooled = (float*)(ws + alloc((size_t)(NGRAPHS * 64 + NGRAPHS) * 4));
    float* cntg = pooled + NGRAPHS * 64;

    hipMemsetAsync(cnt, 0, (size_t)N * 4, stream);
    hipMemsetAsync(stats, 0, 4 * 256 * 4, stream);
    hipMemsetAsync(pooled, 0, (size_t)(NGRAPHS * 64 + NGRAPHS) * 4, stream);

    const int ebl = (E + 255) / 256;
    const int nbl = (N + 255) / 256;
    const int NB = nbl;  // scan blocks (<=512)
    const float invN = 1.0f / (float)N;
    const int gbl = (N + 3) / 4;  // gather: 4 waves/block, 1 wave/node
    const int sbl = 512;          // stats grid

    // ---- CSR build ----
    k_degree<<<ebl, 256, 0, stream>>>(dst, cnt, E);
    k_scan1<<<NB, 256, 0, stream>>>(cnt, bsum, N);
    k_scan2<<<1, 512, 0, stream>>>(bsum, NB);
    k_scan3<<<NB, 256, 0, stream>>>(cnt, bsum, row_start, cursor, N);
    k_fill<<<ebl, 256, 0, stream>>>(src, dst, cursor, csr, E);

    // ---- Layer 1 (64 -> 16): matmul first, aggregate 16 channels ----
    k_mm_rel1<<<nbl, 256, 0, stream>>>(x, w_rel1, y1, N);
    k_gather<16><<<gbl, 256, 0, stream>>>(y1, row_start, csr, agg, N);
    k_node<64, 16, true><<<nbl, 256, 0, stream>>>(x, agg, nullptr, w_root1, b1, bufA, N);
    k_stats<16><<<sbl, 256, 0, stream>>>(bufA, stats + 0, N);
    k_bn_elu<16><<<(N * 4 + 255) / 256, 256, 0, stream>>>(bufA, stats + 0, g1, be1, N, invN);

    // ---- Layer 2 (16 -> 32) ----
    k_gather<16><<<gbl, 256, 0, stream>>>(bufA, row_start, csr, agg, N);
    k_node<16, 32, false><<<nbl, 256, 0, stream>>>(bufA, agg, w_rel2, w_root2, b2, bufB, N);
    k_stats<32><<<sbl, 256, 0, stream>>>(bufB, stats + 256, N);
    k_bn_elu<32><<<(N * 8 + 255) / 256, 256, 0, stream>>>(bufB, stats + 256, g2, be2, N, invN);

    // ---- Layer 3 (32 -> 32) ----
    k_gather<32><<<gbl, 256, 0, stream>>>(bufB, row_start, csr, agg, N);
    k_node<32, 32, false><<<nbl, 256, 0, stream>>>(bufB, agg, w_rel3, w_root3, b3, bufA, N);
    k_stats<32><<<sbl, 256, 0, stream>>>(bufA, stats + 512, N);
    k_bn_elu<32><<<(N * 8 + 255) / 256, 256, 0, stream>>>(bufA, stats + 512, g3, be3, N, invN);

    // ---- Layer 4 (32 -> 64) ----
    k_gather<32><<<gbl, 256, 0, stream>>>(bufA, row_start, csr, agg, N);
    k_node<32, 64, false><<<nbl, 256, 0, stream>>>(bufA, agg, w_rel4, w_root4, b4, bufB, N);
    k_stats<64><<<sbl, 256, 0, stream>>>(bufB, stats + 768, N);
    k_bn_elu<64><<<(N * 16 + 255) / 256, 256, 0, stream>>>(bufB, stats + 768, g4, be4, N, invN);

    // ---- global mean pool + head ----
    int waves = (N + 63) / 64;
    k_pool<<<(waves + 3) / 4, 256, 0, stream>>>(bufB, batch, pooled, cntg, N);
    k_head<<<1, 256, 0, stream>>>(pooled, cntg, w_lin1, b_lin1, w_lin2, b_lin2, (float*)d_out);
}